// Round 9
// baseline (873.629 us; speedup 1.0000x reference)
//
#include <hip/hip_runtime.h>
#include <stdint.h>

// Problem constants (fixed by reference: B=2, S=2048, IN=4096, OUT=11008, G=128)
// Reference dtypes: hidden_states fp16 -> device float32; qweight int32;
// scales fp16 -> device float32; output fp16 -> device float32 ("else float*").
#define MDIM 4096            // B*S
#define KDIM 4096            // in_features
#define NDIM 11008           // out_features
#define PACKN (NDIM / 8)     // 1376 int32 per K-row
#define NT (NDIM / 128)      // 86 n-tiles
#define MT (MDIM / 128)      // 32 m-tiles

typedef __attribute__((ext_vector_type(8))) _Float16 half8;
typedef __attribute__((ext_vector_type(4))) float f32x4;
typedef __attribute__((ext_vector_type(4))) unsigned int uint32x4;

// ---------------------------------------------------------------------------
// Fused AWQ GEMM, f32-in/f32-out. 128x128 tile, BK=64, 256 threads = 4 waves
// (2x2), 4x4 16x16x32 f16 MFMA frags/wave. Per K-step each block dequantizes
// its own 128n x 64k B-tile into LDS as fp16 (magic-exponent int4->f32), and
// stages the A-tile f32->fp16 (lossless: values are fp16-origin).
// ---------------------------------------------------------------------------
__global__ __launch_bounds__(256) void awq_fused(
    const float* __restrict__ A, const int* __restrict__ qw,
    const float* __restrict__ sc, float* __restrict__ C)
{
    __shared__ __align__(16) _Float16 As[128 * 64];
    __shared__ __align__(16) _Float16 Bs[128 * 64];

    const int nwg = MT * NT;                 // 2752, % 8 == 0
    const int cpx = nwg >> 3;
    const int bid = blockIdx.x;
    const int swz = (bid & 7) * cpx + (bid >> 3);   // bijective XCD swizzle
    const int mb = swz / NT;
    const int nb = swz % NT;

    const int t = threadIdx.x, lane = t & 63, wv = t >> 6;
    const int wm = wv >> 1, wn = wv & 1;     // 2x2 wave grid (64x64 each)
    const size_t m0 = (size_t)mb * 128;
    const int n0 = nb * 128;                 // global n of tile start
    const int cp0 = n0 >> 3;                 // int32 col base (16 per tile)

    f32x4 acc[4][4];
#pragma unroll
    for (int i = 0; i < 4; ++i)
#pragma unroll
        for (int j = 0; j < 4; ++j) acc[i][j] = (f32x4){0.f, 0.f, 0.f, 0.f};

    const int lrow = lane >> 3;              // 0..7
    const int lkel = (lane & 7) * 8;         // 0..56 (f32 elements)

    float svf[4][8];                         // per-group scales (32 n values, f32)

    for (int kt = 0; kt < KDIM / 64; ++kt) {
        const int kk = kt * 64;
        // ---- A stage: global f32 -> regs (2x float4 per 8-elem chunk) ----
        f32x4 va0[4], va1[4];
#pragma unroll
        for (int i = 0; i < 4; ++i) {
            const size_t row = m0 + (size_t)((i * 4 + wv) * 8 + lrow);
            va0[i] = *reinterpret_cast<const f32x4*>(&A[row * KDIM + kk + lkel]);
            va1[i] = *reinterpret_cast<const f32x4*>(&A[row * KDIM + kk + lkel + 4]);
        }
        // ---- qweight tile: thread handles k-row = lane, int32 cols wv*4..+3 ----
        const uint32x4 qv = *reinterpret_cast<const uint32x4*>(
            &qw[(size_t)(kk + lane) * PACKN + cp0 + wv * 4]);
        // ---- scales (f32): reload on group boundary (every 2 K-steps) ----
        if ((kt & 1) == 0) {
            const int g = kk >> 7;
#pragma unroll
            for (int i = 0; i < 4; ++i) {
                const f32x4 s0 = *reinterpret_cast<const f32x4*>(
                    &sc[(size_t)g * NDIM + n0 + (wv * 4 + i) * 8]);
                const f32x4 s1 = *reinterpret_cast<const f32x4*>(
                    &sc[(size_t)g * NDIM + n0 + (wv * 4 + i) * 8 + 4]);
#pragma unroll
                for (int j = 0; j < 4; ++j) { svf[i][j] = s0[j]; svf[i][j + 4] = s1[j]; }
            }
        }
        __syncthreads();                     // prior iter's frag reads done
        // ---- write A tile (f32 -> fp16, exact for fp16-origin data) ----
#pragma unroll
        for (int i = 0; i < 4; ++i) {
            half8 h;
#pragma unroll
            for (int j = 0; j < 4; ++j) {
                h[j]     = (_Float16)va0[i][j];
                h[j + 4] = (_Float16)va1[i][j];
            }
            *reinterpret_cast<half8*>(
                &As[((i * 4 + wv) * 8 + lrow) * 64 + lkel]) = h;
        }
        // ---- dequant + write B tile: Bs[n_local][k], n_local = (wv*4+i)*8+j,
        //      k = lane. Wave writes one 128-half row per (i,j): 2-way bank
        //      alias = free. Magic: 0x43000000|(nib<<16) = 128+nib (f32). ----
#pragma unroll
        for (int i = 0; i < 4; ++i) {
            const unsigned int q = qv[i];
#pragma unroll
            for (int j = 0; j < 8; ++j) {
                const unsigned int nib =
                    (j < 4) ? ((q << (16 - 4 * j)) & 0x000F0000u)
                            : ((q >> (4 * j - 16)) & 0x000F0000u);
                union { unsigned int u; float f; } F; F.u = 0x43000000u | nib;
                const float w = F.f - 136.0f;              // nibble - 8
                Bs[((wv * 4 + i) * 8 + j) * 64 + lane] = (_Float16)(w * svf[i][j]);
            }
        }
        __syncthreads();                     // tile visible to all waves
        // ---- MFMA (f16 variant; layout identical to bf16) ----
#pragma unroll
        for (int ks = 0; ks < 2; ++ks) {
            half8 af[4], bfr[4];
#pragma unroll
            for (int mi = 0; mi < 4; ++mi)
                af[mi] = *reinterpret_cast<const half8*>(
                    &As[(wm * 64 + mi * 16 + (lane & 15)) * 64 + ks * 32 + (lane >> 4) * 8]);
#pragma unroll
            for (int ni = 0; ni < 4; ++ni)
                bfr[ni] = *reinterpret_cast<const half8*>(
                    &Bs[(wn * 64 + ni * 16 + (lane & 15)) * 64 + ks * 32 + (lane >> 4) * 8]);
#pragma unroll
            for (int mi = 0; mi < 4; ++mi)
#pragma unroll
                for (int ni = 0; ni < 4; ++ni)
                    acc[mi][ni] = __builtin_amdgcn_mfma_f32_16x16x32_f16(
                        af[mi], bfr[ni], acc[mi][ni], 0, 0, 0);
        }
    }

    // Epilogue: C/D layout col = lane&15 (n), row = (lane>>4)*4 + r (m).
    // Output buffer is f32 -> store accumulator directly (no rounding loss).
    const int orow = (lane >> 4) * 4;
    const int ocol = lane & 15;
#pragma unroll
    for (int mi = 0; mi < 4; ++mi) {
#pragma unroll
        for (int r = 0; r < 4; ++r) {
            const size_t row = m0 + wm * 64 + mi * 16 + orow + r;
#pragma unroll
            for (int ni = 0; ni < 4; ++ni) {
                const size_t col = (size_t)(n0 + wn * 64 + ni * 16 + ocol);
                C[row * NDIM + col] = acc[mi][ni][r];
            }
        }
    }
}

// ---------------------------------------------------------------------------
extern "C" void kernel_launch(void* const* d_in, const int* in_sizes, int n_in,
                              void* d_out, int out_size, void* d_ws, size_t ws_size,
                              hipStream_t stream) {
    // Defensive input binding: identify by element count (all distinct).
    const float* A  = nullptr;  // hidden_states: 2*2048*4096 = 16,777,216 (f32)
    const int* qw   = nullptr;  // qweight:       4096*1376  =  5,636,096 (i32)
    const float* sc = nullptr;  // scales:        32*11008   =    352,256 (f32)
    for (int i = 0; i < n_in; ++i) {
        if (in_sizes[i] == MDIM * KDIM)              A  = (const float*)d_in[i];
        else if (in_sizes[i] == KDIM * PACKN)        qw = (const int*)d_in[i];
        else if (in_sizes[i] == (KDIM / 128) * NDIM) sc = (const float*)d_in[i];
    }
    if (!A)  A  = (const float*)d_in[0];
    if (!qw) qw = (const int*)d_in[1];
    if (!sc) sc = (const float*)d_in[2];
    float* out = (float*)d_out;

    awq_fused<<<dim3(MT * NT), dim3(256), 0, stream>>>(A, qw, sc, out);
    (void)d_ws; (void)ws_size;
}